// Round 5
// baseline (409.721 us; speedup 1.0000x reference)
//
#include <hip/hip_runtime.h>
#include <math.h>

#define NRAYS 65536
#define T0N 128
#define T1N 64
#define CN 16
#define RPB 4                   // rays (waves) per block
#define NBLK (NRAYS / RPB)      // 16384

#define IMG_OFF   0
#define DEPTH_OFF (NRAYS * 3)
#define FXYZ_OFF  (NRAYS * 4)
#define PROP_OFF  (NRAYS * 7)
#define DIST_OFF  (NRAYS * 7 + 1)

// v_rcp_f32: 1-ulp reciprocal; threshold 1.57e-2 abs with 4x margin.
__device__ __forceinline__ float frcp(float x) { return __builtin_amdgcn_rcpf(x); }

// ---- DPP cross-lane (VALU pipe) ----
template <int CTRL, int RM, int BM, bool BC>
__device__ __forceinline__ int dpp_add_i(int x) {
  int t = __builtin_amdgcn_update_dpp(0, x, CTRL, RM, BM, BC);
  return x + t;
}
template <int CTRL, int RM, int BM, bool BC>
__device__ __forceinline__ float dpp_add(float x) {
  int t = __builtin_amdgcn_update_dpp(0, __float_as_int(x), CTRL, RM, BM, BC);
  return x + __int_as_float(t);
}

__device__ __forceinline__ float scan_incl(float x) {   // 64-lane inclusive scan
  x = dpp_add<0x111, 0xF, 0xF, true>(x);   // row_shr:1
  x = dpp_add<0x112, 0xF, 0xF, true>(x);   // row_shr:2
  x = dpp_add<0x114, 0xF, 0xF, true>(x);   // row_shr:4
  x = dpp_add<0x118, 0xF, 0xF, true>(x);   // row_shr:8
  x = dpp_add<0x142, 0xA, 0xF, false>(x);  // row_bcast:15
  x = dpp_add<0x143, 0xC, 0xF, false>(x);  // row_bcast:31
  return x;
}
__device__ __forceinline__ int scan_incl_i(int x) {
  x = dpp_add_i<0x111, 0xF, 0xF, true>(x);
  x = dpp_add_i<0x112, 0xF, 0xF, true>(x);
  x = dpp_add_i<0x114, 0xF, 0xF, true>(x);
  x = dpp_add_i<0x118, 0xF, 0xF, true>(x);
  x = dpp_add_i<0x142, 0xA, 0xF, false>(x);
  x = dpp_add_i<0x143, 0xC, 0xF, false>(x);
  return x;
}
__device__ __forceinline__ float reduce_hi(float x) {   // total in lanes 48-63
  x = dpp_add<0xB1, 0xF, 0xF, true>(x);
  x = dpp_add<0x4E, 0xF, 0xF, true>(x);
  x = dpp_add<0x141, 0xF, 0xF, true>(x);
  x = dpp_add<0x140, 0xF, 0xF, true>(x);
  x = dpp_add<0x142, 0xA, 0xF, false>(x);
  x = dpp_add<0x143, 0xC, 0xF, false>(x);
  return x;
}
__device__ __forceinline__ float rlane(float x, int l) {
  return __int_as_float(__builtin_amdgcn_readlane(__float_as_int(x), l));
}

// Wave-internal LDS producer->consumer sync (arrays are wave-private).
__device__ __forceinline__ void wave_lds_sync() {
  __builtin_amdgcn_wave_barrier();
  __builtin_amdgcn_fence(__ATOMIC_ACQ_REL, "workgroup");
  __builtin_amdgcn_wave_barrier();
}

__device__ __forceinline__ float spacing_fn(float x) {
  return (x < 1.0f) ? (x * 0.5f) : (1.0f - 0.5f * frcp(x));
}
__device__ __forceinline__ float spacing_inv_fn(float x) {
  return (x < 0.5f) ? (2.0f * x) : frcp(2.0f - 2.0f * x);
}

// First u-bucket j (u_j=(j+0.5)/65) with c <= u_j; fixup makes it bit-exact
// vs the consumer compare c <= (j+0.5f)*(1/65.0f). Entry contributes to all
// counts[j], j >= k. k==65 -> never counts (trash bucket).
__device__ __forceinline__ int ubucket(float c) {
  int k = (int)ceilf(fmaf(65.0f, c, -0.5f));
  k = max(0, min(k, 65));
  if (k > 0 && c <= ((float)(k - 1) + 0.5f) * (1.0f / 65.0f)) k -= 1;
  else if (k < 65 && !(c <= ((float)k + 0.5f) * (1.0f / 65.0f))) k += 1;
  return k;
}

__global__ void __launch_bounds__(256, 4) nerf_main(
    const float* __restrict__ rays_o, const float* __restrict__ rays_d,
    const float* __restrict__ aabb, const float* __restrict__ sig_c,
    const float* __restrict__ sig_f, const float* __restrict__ colors,
    const float* __restrict__ w_view, const float* __restrict__ b_view,
    float* __restrict__ out, float* __restrict__ ws_partials, int use_atomic) {
  __shared__ float s_cdf[RPB][132];               // 129 used
  __shared__ float s_cw1[RPB][68];                // 65 used
  __shared__ int   s_hu[RPB][68];                 // 65 u-buckets + trash
  __shared__ int   s_hi[RPB][132];                // 129 i-buckets + trash
  __shared__ __align__(16) float s_col[RPB][1024];
  __shared__ float s_scal[RPB][2];

  const int wv = threadIdx.x >> 6;
  const int lane = threadIdx.x & 63;
  const int ray = blockIdx.x * RPB + wv;
  const int tg = lane >> 2, cg = lane & 3;

  // ---- colors: async DMA global->LDS (no VGPR cost, overlaps whole kernel)
  {
    const float* gcol = colors + (size_t)ray * (T1N * CN);
#pragma unroll
    for (int q = 0; q < 4; ++q) {
      __builtin_amdgcn_global_load_lds(
          (const __attribute__((address_space(1))) void*)(gcol + q * 256 + lane * 4),
          (__attribute__((address_space(3))) void*)(&s_col[wv][q * 256]),
          16, 0, 0);
    }
  }
  const float2 sg = ((const float2*)sig_c)[ray * 64 + lane];
  const float sgf = sig_f[ray * 64 + lane];

  // ---- zero histograms (ordered before atomics by sync #0 below)
  s_hu[wv][lane] = 0;
  if (lane < 4) s_hu[wv][64 + lane] = 0;
  s_hi[wv][2 * lane] = 0;
  s_hi[wv][2 * lane + 1] = 0;
  if (lane < 4) s_hi[wv][128 + lane] = 0;

  // ---- ray setup
  float ro[3], rd[3];
#pragma unroll
  for (int c = 0; c < 3; ++c) { ro[c] = rays_o[ray * 3 + c]; rd[c] = rays_d[ray * 3 + c]; }
  float near = -3.0e38f, far = 3.0e38f;
#pragma unroll
  for (int c = 0; c < 3; ++c) {
    const float rdd = frcp(rd[c] + 1e-15f);
    float ta = (aabb[c] - ro[c]) * rdd;
    float tb = (aabb[c + 3] - ro[c]) * rdd;
    near = fmaxf(near, fminf(ta, tb));
    far = fminf(far, fmaxf(ta, tb));
  }
  if (far < near) { near = 1e9f; far = 1e9f; }
  near = fmaxf(near, 0.05f);
  const float s_near = spacing_fn(near), s_far = spacing_fn(far);
  wave_lds_sync();  // #0: hist zeroing visible before atomics

  // ---- coarse level: lane owns bins0 samples 2l, 2l+1
  const int i0 = 2 * lane, i1 = 2 * lane + 1;
  const float b_a = (float)i0 * (1.0f / 128.0f);
  const float b_b = (float)i1 * (1.0f / 128.0f);
  const float b_c = (float)(i1 + 1) * (1.0f / 128.0f);
  const float rb_a = spacing_inv_fn(s_near * (1.0f - b_a) + s_far * b_a);
  const float rb_b = spacing_inv_fn(s_near * (1.0f - b_b) + s_far * b_b);
  const float rb_c = spacing_inv_fn(s_near * (1.0f - b_c) + s_far * b_c);
  const float ds0 = (rb_b - rb_a) * sg.x;
  const float ds1 = (rb_c - rb_b) * sg.y;
  const float Spr = scan_incl(ds0 + ds1);
  const float E0 = Spr - (ds0 + ds1);
  const float e0 = __expf(-E0);
  const float ed0 = __expf(-ds0);
  float w00 = (1.0f - ed0) * e0;
  float w01 = (1.0f - __expf(-ds1)) * (e0 * ed0);
  if (w00 != w00) w00 = 0.0f;  // nan_to_num
  if (w01 != w01) w01 = 0.0f;

  // ---- cdf (LDS, for interpolation) + u-histogram (replaces binary search)
  const float wp0 = w00 + 0.01f, wp1 = w01 + 0.01f;
  const float S2 = scan_incl(wp0 + wp1);
  const float rt = frcp(rlane(S2, 63));
  const float cdf_o = fminf((S2 - wp1) * rt, 1.0f);   // entry 2l+1
  const float cdf_e = fminf(S2 * rt, 1.0f);           // entry 2l+2
  s_cdf[wv][i0 + 1] = cdf_o;
  s_cdf[wv][i1 + 1] = cdf_e;
  if (lane == 0) s_cdf[wv][0] = 0.0f;
  atomicAdd(&s_hu[wv][ubucket(cdf_o)], 1);
  atomicAdd(&s_hu[wv][ubucket(cdf_e)], 1);
  wave_lds_sync();  // #1: cdf + u-hist complete

  // ---- inverse-CDF sampling: counts from scanned histogram (chain len 1)
  const int hu_l = s_hu[wv][lane];
  const int h64 = s_hu[wv][64];
  const int Su = scan_incl_i(hu_l);   // cum buckets 0..lane
  auto interp = [&](int c, float u) -> float {
    c = min(c, 128);
    const float c0 = s_cdf[wv][c - 1], c1 = s_cdf[wv][c];
    float t = (u - c0) * frcp(c1 - c0);
    t = fminf(fmaxf(t, 0.0f), 1.0f);  // NaN->0, inf->1 == nan_to_num+clip
    return (float)(c - 1) * (1.0f / 128.0f) + t * (1.0f / 128.0f);
  };
  const float bv = interp(1 + Su, ((float)lane + 0.5f) * (1.0f / 65.0f));
  float bv64s = 0.0f;
  if (lane == 63) bv64s = interp(1 + Su + h64, 64.5f * (1.0f / 65.0f));
  float bvn = __shfl_down(bv, 1, 64);
  if (lane == 63) bvn = bv64s;

  // ---- i-histogram for interlevel (exact: 128*b is exact in fp32)
  {
    int ki = (int)ceilf(bv * 128.0f);
    ki = max(0, min(ki, 129));
    atomicAdd(&s_hi[wv][ki], 1);
    if (lane == 63) {
      int k2 = (int)ceilf(bv64s * 128.0f);
      k2 = max(0, min(k2, 129));
      atomicAdd(&s_hi[wv][k2], 1);
    }
  }

  // ---- fine level
  const float rbl  = spacing_inv_fn(s_near * (1.0f - bv)  + s_far * bv);
  const float rbl1 = spacing_inv_fn(s_near * (1.0f - bvn) + s_far * bvn);
  const float dsf = (rbl1 - rbl) * sgf;
  const float Sf = scan_incl(dsf);
  float w1 = (1.0f - __expf(-dsf)) * __expf(-(Sf - dsf));
  if (w1 != w1) w1 = 0.0f;
  const float tmid = 0.5f * (rbl + rbl1);

  // xyz + MERF contraction
  float px = ro[0] + rd[0] * tmid;
  float py = ro[1] + rd[1] * tmid;
  float pz = ro[2] + rd[2] * tmid;
  float cx = px, cy = py, cz = pz;
  {
    float ax = fabsf(px), ay = fabsf(py), az = fabsf(pz);
    float mag = fmaxf(ax, fmaxf(ay, az));
    if (mag >= 1.0f) {
      float inv = frcp(mag);
      float so = (2.0f - inv) * inv;
      int idx = (ax >= ay && ax >= az) ? 0 : ((ay >= az) ? 1 : 2);
      cx = px * (idx == 0 ? so : inv);
      cy = py * (idx == 1 ? so : inv);
      cz = pz * (idx == 2 ? so : inv);
    }
  }

  const float Scw = scan_incl(w1);
  const float wsum = rlane(Scw, 63);
  const float depth_h = reduce_hi(w1 * tmid);   // totals valid lanes 48-63
  const float fx_h = reduce_hi(w1 * cx);
  const float fy_h = reduce_hi(w1 * cy);
  const float fz_h = reduce_hi(w1 * cz);
  s_cw1[wv][lane + 1] = Scw;
  if (lane == 0) s_cw1[wv][0] = 0.0f;

  // ---- distortion loss
  const float interval = bvn - bv;
  const float mid = bv + interval * 0.5f;
  const float wm = w1 * mid;
  const float Swm = scan_incl(wm);
  const float dl = (1.0f / 3.0f) * (interval * w1 * w1) +
                   2.0f * (wm * (Scw - w1) - w1 * (Swm - wm));
  const float dist_h = reduce_hi(dl);
  wave_lds_sync();  // #2: i-hist + cw1 complete

  // ---- interlevel loss via cumulative i-histogram (no searches)
  float prop_lane = 0.0f;
  {
    const int ha = s_hi[wv][2 * lane];
    const int hb = s_hi[wv][2 * lane + 1];
    const int hc = s_hi[wv][2 * lane + 2];
    const int C1 = scan_incl_i(ha + hb);   // C[2l+1] = #{j: bins1[j] <= (2l+1)/128}
    const int C0 = C1 - hb;                // C[2l]
    const int C2 = C1 + hc;                // C[2l+2]
    const float b1_0 = rlane(bv, 0);
    const float b1_64 = rlane(bv64s, 63);
    const float* cwp = &s_cw1[wv][0];
#pragma unroll
    for (int k = 0; k < 2; ++k) {
      const int i = 2 * lane + k;
      const float w0v = (k == 0) ? w00 : w01;
      const float vlo = (float)i * (1.0f / 128.0f);
      const float vhi = (float)(i + 1) * (1.0f / 128.0f);
      const int Ci = (k == 0) ? C0 : C1;
      const int Ci1 = (k == 0) ? C1 : C2;
      int ilo = min(max(Ci - (b1_64 <= vlo ? 1 : 0) - 1, 0), 63);
      int ihi = min(max(Ci1 - (b1_0 <= vhi ? 1 : 0), 0), 63);
      float wint = cwp[ihi + 1] - cwp[ilo];
      float diff = fmaxf(w0v - wint, 0.0f);
      prop_lane += diff * diff * frcp(w0v + 1e-8f);
    }
  }
  const float prop_h = reduce_hi(prop_lane);

  // ---- colors from LDS (DMA long since landed); fused w_view matvec
  __builtin_amdgcn_s_waitcnt(0x0F70);  // vmcnt(0) only
  __builtin_amdgcn_wave_barrier();
  float acc0, acc1, acc2;
  {
    const float* cb = &s_col[wv][0];
    const float4 cva = *(const float4*)(cb + (tg + 0) * 16 + cg * 4);
    const float4 cvb = *(const float4*)(cb + (tg + 16) * 16 + cg * 4);
    const float4 cvc = *(const float4*)(cb + (tg + 32) * 16 + cg * 4);
    const float4 cvd = *(const float4*)(cb + (tg + 48) * 16 + cg * 4);
    const float wv0 = __shfl(w1, tg, 64);
    const float wv1 = __shfl(w1, tg + 16, 64);
    const float wv2 = __shfl(w1, tg + 32, 64);
    const float wv3 = __shfl(w1, tg + 48, 64);
    const float a0 = fmaf(wv0, cva.x, fmaf(wv1, cvb.x, fmaf(wv2, cvc.x, wv3 * cvd.x)));
    const float a1 = fmaf(wv0, cva.y, fmaf(wv1, cvb.y, fmaf(wv2, cvc.y, wv3 * cvd.y)));
    const float a2 = fmaf(wv0, cva.z, fmaf(wv1, cvb.z, fmaf(wv2, cvc.z, wv3 * cvd.z)));
    const float a3 = fmaf(wv0, cva.w, fmaf(wv1, cvb.w, fmaf(wv2, cvc.w, wv3 * cvd.w)));
    const float* wvp = w_view + cg * 12;  // rows for channels 4cg..4cg+3
    acc0 = reduce_hi(fmaf(a0, wvp[0], fmaf(a1, wvp[3], fmaf(a2, wvp[6], a3 * wvp[9]))));
    acc1 = reduce_hi(fmaf(a0, wvp[1], fmaf(a1, wvp[4], fmaf(a2, wvp[7], a3 * wvp[10]))));
    acc2 = reduce_hi(fmaf(a0, wvp[2], fmaf(a1, wvp[5], fmaf(a2, wvp[8], a3 * wvp[11]))));
  }

  // ---- epilogue: totals live in lanes 48-63; writes spread over 48-52
  if (lane >= 48 && lane < 51) {
    const int j = lane - 48;
    float acc = (j == 0) ? acc0 : ((j == 1) ? acc1 : acc2);
    acc += b_view[j];
    out[IMG_OFF + ray * 3 + j] = frcp(1.0f + __expf(-acc)) + (1.0f - wsum);
    out[FXYZ_OFF + ray * 3 + j] = (j == 0) ? fx_h : ((j == 1) ? fy_h : fz_h);
  }
  if (lane == 51) out[DEPTH_OFF + ray] = depth_h;
  if (lane == 52) { s_scal[wv][0] = prop_h; s_scal[wv][1] = dist_h; }
  __syncthreads();  // only cross-wave communication
  if (threadIdx.x == 0) {
    float P = s_scal[0][0] + s_scal[1][0] + s_scal[2][0] + s_scal[3][0];
    float D = s_scal[0][1] + s_scal[1][1] + s_scal[2][1] + s_scal[3][1];
    if (use_atomic) {
      atomicAdd(out + PROP_OFF, P * (1.0f / ((float)NRAYS * 128.0f)));
      atomicAdd(out + DIST_OFF, D * (1.0f / (float)NRAYS));
    } else {
      ws_partials[blockIdx.x] = P;
      ws_partials[NBLK + blockIdx.x] = D;
    }
  }
}

__device__ __forceinline__ float wave_sum_shfl(float x) {
#pragma unroll
  for (int off = 1; off < 64; off <<= 1) x += __shfl_xor(x, off, 64);
  return x;
}

__global__ void __launch_bounds__(256) reduce_partials(const float* __restrict__ ws,
                                                       float* __restrict__ out) {
  const float4* w4 = (const float4*)ws;
  float p = 0.0f, d = 0.0f;
  for (int i = threadIdx.x; i < NBLK / 4; i += 256) {
    float4 a = w4[i];
    p += (a.x + a.y) + (a.z + a.w);
    float4 b = w4[NBLK / 4 + i];
    d += (b.x + b.y) + (b.z + b.w);
  }
  p = wave_sum_shfl(p);
  d = wave_sum_shfl(d);
  __shared__ float sp[4], sd[4];
  const int wv = threadIdx.x >> 6, lane = threadIdx.x & 63;
  if (lane == 0) { sp[wv] = p; sd[wv] = d; }
  __syncthreads();
  if (threadIdx.x == 0) {
    float P = sp[0] + sp[1] + sp[2] + sp[3];
    float D = sd[0] + sd[1] + sd[2] + sd[3];
    out[PROP_OFF] = P * (1.0f / ((float)NRAYS * 128.0f));
    out[DIST_OFF] = D * (1.0f / (float)NRAYS);
  }
}

extern "C" void kernel_launch(void* const* d_in, const int* in_sizes, int n_in,
                              void* d_out, int out_size, void* d_ws, size_t ws_size,
                              hipStream_t stream) {
  const float* rays_o = (const float*)d_in[0];
  const float* rays_d = (const float*)d_in[1];
  const float* aabb = (const float*)d_in[2];
  const float* sig_c = (const float*)d_in[3];
  const float* sig_f = (const float*)d_in[4];
  const float* colors = (const float*)d_in[5];
  const float* w_view = (const float*)d_in[6];
  const float* b_view = (const float*)d_in[7];
  float* out = (float*)d_out;
  float* wsf = (float*)d_ws;

  const bool use_ws = (ws_size >= (size_t)(2 * NBLK) * sizeof(float)) && (wsf != nullptr);
  if (!use_ws) {
    hipMemsetAsync(out + PROP_OFF, 0, 2 * sizeof(float), stream);
  }
  nerf_main<<<NBLK, 256, 0, stream>>>(rays_o, rays_d, aabb, sig_c, sig_f, colors,
                                      w_view, b_view, out, wsf, use_ws ? 0 : 1);
  if (use_ws) reduce_partials<<<1, 256, 0, stream>>>(wsf, out);
}